// Round 6
// baseline (698.395 us; speedup 1.0000x reference)
//
#include <hip/hip_runtime.h>
#include <hip/hip_bf16.h>
#include <stdint.h>

#define T_TOK 16384
#define D_DIM 4096
#define E_EXP 256

typedef __attribute__((ext_vector_type(8))) short bf16x8;
typedef __attribute__((ext_vector_type(4))) float f32x4;

__device__ __forceinline__ uint32_t bf16_rne(float f) {
    uint32_t u = __float_as_uint(f);
    return (u + 0x7FFFu + ((u >> 16) & 1u)) >> 16;
}

// ---------------------------------------------------------------------------
// Kernel 0: split W into 3 bf16 terms (h+m+l, RNE at each level) + zero accs.
// ---------------------------------------------------------------------------
__global__ __launch_bounds__(256)
void wsplit_kernel(const float* __restrict__ W, uint16_t* __restrict__ Wh,
                   uint16_t* __restrict__ Wm, uint16_t* __restrict__ Wl,
                   float* __restrict__ acc512) {
    const int idx = blockIdx.x * 256 + threadIdx.x;  // 0..262143 float4s
    const float4 v = ((const float4*)W)[idx];
    const float f[4] = {v.x, v.y, v.z, v.w};
    uint32_t h[4], m[4], l[4];
    #pragma unroll
    for (int j = 0; j < 4; ++j) {
        h[j] = bf16_rne(f[j]);
        const float r1 = f[j] - __uint_as_float(h[j] << 16);  // exact
        m[j] = bf16_rne(r1);
        const float r2 = r1 - __uint_as_float(m[j] << 16);    // exact
        l[j] = bf16_rne(r2);
    }
    ((uint2*)Wh)[idx] = make_uint2(h[0] | (h[1] << 16), h[2] | (h[3] << 16));
    ((uint2*)Wm)[idx] = make_uint2(m[0] | (m[1] << 16), m[2] | (m[3] << 16));
    ((uint2*)Wl)[idx] = make_uint2(l[0] | (l[1] << 16), l[2] | (l[3] << 16));
    if (blockIdx.x == 0) {
        acc512[threadIdx.x] = 0.0f;
        acc512[threadIdx.x + 256] = 0.0f;
    }
}

// ---------------------------------------------------------------------------
// Kernel 1 (FUSED): logits tile = x @ W^T (split-3 bf16, 6 MFMA products)
// + in-block softmax / grouped top-k router.
// R6 CHANGE: tile 64tok -> 32tok, grid 256 -> 512 blocks. Occupancy was
// grid-limited to 1 block/CU (8 waves/CU, 23%); now 2 blocks/CU = 16
// waves/CU. Per-(token,expert) MFMA chains keep the same k-order and
// product order -> logits bit-identical to R5.
// ---------------------------------------------------------------------------
#define LDK 72
#define BUFE 2304   // 32 * LDK uint16 per stream per buffer
#define SROW 272    // f32 row stride of the LDS logits tile (bank-spread)

#define LOADB(bh, bm, bl, ko) do { \
    _Pragma("unroll") \
    for (int nt = 0; nt < 2; ++nt) { \
        const uint32_t o = woff[nt] + (uint32_t)(ko); \
        bh[nt] = *(const bf16x8*)(Wh + o); \
        bm[nt] = *(const bf16x8*)(Wm + o); \
        bl[nt] = *(const bf16x8*)(Wl + o); \
    } } while (0)

#define SPLIT_STORE(buf) do { \
    const float f[4] = {p.x, p.y, p.z, p.w}; \
    uint32_t h[4], m[4], l[4]; \
    _Pragma("unroll") \
    for (int j = 0; j < 4; ++j) { \
        h[j] = bf16_rne(f[j]); \
        const float r1 = f[j] - __uint_as_float(h[j] << 16); \
        m[j] = bf16_rne(r1); \
        const float r2 = r1 - __uint_as_float(m[j] << 16); \
        l[j] = bf16_rne(r2); \
    } \
    *(uint2*)&sXh[(buf) * BUFE + swoff] = \
        make_uint2(h[0] | (h[1] << 16), h[2] | (h[3] << 16)); \
    *(uint2*)&sXm[(buf) * BUFE + swoff] = \
        make_uint2(m[0] | (m[1] << 16), m[2] | (m[3] << 16)); \
    *(uint2*)&sXl[(buf) * BUFE + swoff] = \
        make_uint2(l[0] | (l[1] << 16), l[2] | (l[3] << 16)); \
} while (0)

#define COMPUTE(buf, s, bh, bm, bl) do { \
    bf16x8 ah[2], am[2], al[2]; \
    _Pragma("unroll") \
    for (int mt = 0; mt < 2; ++mt) { \
        const int ro = (buf) * BUFE + (mt * 16 + l16) * LDK + (s) * 32 + quad * 8; \
        ah[mt] = *(const bf16x8*)&sXh[ro]; \
        am[mt] = *(const bf16x8*)&sXm[ro]; \
        al[mt] = *(const bf16x8*)&sXl[ro]; \
    } \
    _Pragma("unroll") \
    for (int mt = 0; mt < 2; ++mt) \
        _Pragma("unroll") \
        for (int nt = 0; nt < 2; ++nt) \
            acc[mt][nt] = __builtin_amdgcn_mfma_f32_16x16x32_bf16(ah[mt], bh[nt], acc[mt][nt], 0, 0, 0); \
    _Pragma("unroll") \
    for (int mt = 0; mt < 2; ++mt) \
        _Pragma("unroll") \
        for (int nt = 0; nt < 2; ++nt) \
            acc[mt][nt] = __builtin_amdgcn_mfma_f32_16x16x32_bf16(ah[mt], bm[nt], acc[mt][nt], 0, 0, 0); \
    _Pragma("unroll") \
    for (int mt = 0; mt < 2; ++mt) \
        _Pragma("unroll") \
        for (int nt = 0; nt < 2; ++nt) \
            acc[mt][nt] = __builtin_amdgcn_mfma_f32_16x16x32_bf16(am[mt], bh[nt], acc[mt][nt], 0, 0, 0); \
    _Pragma("unroll") \
    for (int mt = 0; mt < 2; ++mt) \
        _Pragma("unroll") \
        for (int nt = 0; nt < 2; ++nt) \
            acc[mt][nt] = __builtin_amdgcn_mfma_f32_16x16x32_bf16(am[mt], bm[nt], acc[mt][nt], 0, 0, 0); \
    _Pragma("unroll") \
    for (int mt = 0; mt < 2; ++mt) \
        _Pragma("unroll") \
        for (int nt = 0; nt < 2; ++nt) \
            acc[mt][nt] = __builtin_amdgcn_mfma_f32_16x16x32_bf16(ah[mt], bl[nt], acc[mt][nt], 0, 0, 0); \
    _Pragma("unroll") \
    for (int mt = 0; mt < 2; ++mt) \
        _Pragma("unroll") \
        for (int nt = 0; nt < 2; ++nt) \
            acc[mt][nt] = __builtin_amdgcn_mfma_f32_16x16x32_bf16(al[mt], bh[nt], acc[mt][nt], 0, 0, 0); \
} while (0)

__global__ __launch_bounds__(512, 4)
void gemm_router_kernel(const float* __restrict__ x,
                        const uint16_t* __restrict__ Wh,
                        const uint16_t* __restrict__ Wm,
                        const uint16_t* __restrict__ Wl,
                        float* __restrict__ out_w,
                        float* __restrict__ out_id,
                        float* __restrict__ g_psum,
                        float* __restrict__ g_cnt) {
    // One 36864-byte pool, time-shared:
    //  gemm phase : sXh[2][2304] | sXm[2][2304] | sXl[2][2304]  (uint16)
    //  route phase: sLog f32[32][SROW] (34816 B) | lds_psum[256] | lds_cnt[256]
    __shared__ __align__(16) char pool[36864];
    uint16_t* sXh = (uint16_t*)pool;
    uint16_t* sXm = (uint16_t*)(pool + 9216);
    uint16_t* sXl = (uint16_t*)(pool + 18432);
    float* sLog = (float*)pool;
    float* lds_psum = (float*)(pool + 34816);
    float* lds_cnt = (float*)(pool + 35840);

    const int t = threadIdx.x;
    const int tok0 = blockIdx.x * 32;
    const int wave = t >> 6, lane = t & 63;
    const int quad = lane >> 4, l16 = lane & 15;

    // staging: 512 threads, each handles 4 consecutive k of one token
    const int stok = t >> 4;        // 0..31
    const int skoff = (t & 15) * 4; // 0,4,..,60
    const float* xp = x + (size_t)(tok0 + stok) * D_DIM + skoff;
    const int swoff = stok * LDK + skoff;

    // B pointers: wave covers experts [wave*32, wave*32+32)
    uint32_t woff[2];
    #pragma unroll
    for (int nt = 0; nt < 2; ++nt)
        woff[nt] = (uint32_t)(wave * 32 + nt * 16 + l16) * D_DIM + quad * 8;

    const f32x4 zf = {0.f, 0.f, 0.f, 0.f};
    f32x4 acc[2][2];
    #pragma unroll
    for (int mt = 0; mt < 2; ++mt)
        #pragma unroll
        for (int nt = 0; nt < 2; ++nt) acc[mt][nt] = zf;

    // ---- prologue ----
    float4 p = ((const float4*)xp)[0];
    bf16x8 cbh[2], cbm[2], cbl[2], nbh[2], nbm[2], nbl[2];

    SPLIT_STORE(0);                       // x tile kb=0 -> buf 0
    LOADB(cbh, cbm, cbl, 0);              // B frags (kb=0, s=0)
    p = *(const float4*)(xp + 64);        // prefetch x tile kb=64
    __syncthreads();

    for (int kb = 0; kb < D_DIM; kb += 64) {
        const int cur = (kb >> 6) & 1;
        // ---- phase s=0 ----
        LOADB(nbh, nbm, nbl, kb + 32);            // this k-step, s=1
        COMPUTE(cur, 0, cbh, cbm, cbl);
        // ---- phase s=1 ----
        if (kb + 64 < D_DIM) {
            LOADB(cbh, cbm, cbl, kb + 64);        // next k-step, s=0
            SPLIT_STORE(cur ^ 1);                 // stage next x tile
        }
        if (kb + 128 < D_DIM)                     // prefetch x tile t+2
            p = *(const float4*)(xp + kb + 128);
        COMPUTE(cur, 1, nbh, nbm, nbl);
        __syncthreads();
    }

    // ================= fused router epilogue =================
    if (t < 256) { lds_psum[t] = 0.0f; lds_cnt[t] = 0.0f; }

    // write logits (32 tokens) to LDS.
    // C/D layout: token = mt*16 + quad*4 + r, expert = wave*32 + nt*16 + l16
    #pragma unroll
    for (int u = 0; u < 2; ++u)
        #pragma unroll
        for (int nt = 0; nt < 2; ++nt)
            #pragma unroll
            for (int r = 0; r < 4; ++r)
                sLog[(u * 16 + quad * 4 + r) * SROW + wave * 32 + nt * 16 + l16] =
                    acc[u][nt][r];
    __syncthreads();

    float r0 = 0.f, r1 = 0.f, r2 = 0.f, r3 = 0.f;

    // route 4 tokens per wave (identical math to the standalone router)
    #pragma unroll
    for (int it = 0; it < 4; ++it) {
        const int lrow = wave * 4 + it;          // 0..31
        const int tok = tok0 + lrow;             // global token
        const float4 lg = *(const float4*)&sLog[lrow * SROW + lane * 4];

        float mx = fmaxf(fmaxf(lg.x, lg.y), fmaxf(lg.z, lg.w));
        #pragma unroll
        for (int off = 32; off >= 1; off >>= 1)
            mx = fmaxf(mx, __shfl_xor(mx, off, 64));
        float p0_ = __expf(lg.x - mx);
        float p1_ = __expf(lg.y - mx);
        float p2_ = __expf(lg.z - mx);
        float p3_ = __expf(lg.w - mx);
        float sm = p0_ + p1_ + p2_ + p3_;
        #pragma unroll
        for (int off = 32; off >= 1; off >>= 1)
            sm += __shfl_xor(sm, off, 64);
        const float inv = 1.0f / sm;
        p0_ *= inv; p1_ *= inv; p2_ *= inv; p3_ *= inv;
        r0 += p0_; r1 += p1_; r2 += p2_; r3 += p3_;

        // per-lane top-2 of 4 (ties -> lowest index, matching lax.top_k)
        const int e0 = lane * 4;
        float v1 = p0_, v2 = p1_; int i1 = e0, i2 = e0 + 1;
        if (p1_ > p0_) { v1 = p1_; i1 = e0 + 1; v2 = p0_; i2 = e0; }
        if (p2_ > v1)      { v2 = v1; i2 = i1; v1 = p2_; i1 = e0 + 2; }
        else if (p2_ > v2) { v2 = p2_; i2 = e0 + 2; }
        if (p3_ > v1)      { v2 = v1; i2 = i1; v1 = p3_; i1 = e0 + 3; }
        else if (p3_ > v2) { v2 = p3_; i2 = e0 + 3; }

        // merge top-2 across the 8 lanes of each group
        #pragma unroll
        for (int off = 1; off <= 4; off <<= 1) {
            const float ov1 = __shfl_xor(v1, off, 64);
            const int   oi1 = __shfl_xor(i1, off, 64);
            const float ov2 = __shfl_xor(v2, off, 64);
            const int   oi2 = __shfl_xor(i2, off, 64);
            float n1, n2; int ni1, ni2;
            const bool o_first = (ov1 > v1) || (ov1 == v1 && oi1 < i1);
            if (o_first) {
                n1 = ov1; ni1 = oi1;
                const bool s = (ov2 > v1) || (ov2 == v1 && oi2 < i1);
                n2 = s ? ov2 : v1; ni2 = s ? oi2 : i1;
            } else {
                n1 = v1; ni1 = i1;
                const bool s = (ov1 > v2) || (ov1 == v2 && oi1 < i2);
                n2 = s ? ov1 : v2; ni2 = s ? oi1 : i2;
            }
            v1 = n1; i1 = ni1; v2 = n2; i2 = ni2;
        }

        // gather all 8 groups' results to every lane
        float gv1[8], gv2[8], gsc[8]; int gi1[8], gi2[8];
        #pragma unroll
        for (int g = 0; g < 8; ++g) {
            gv1[g] = __shfl(v1, g * 8, 64);
            gv2[g] = __shfl(v2, g * 8, 64);
            gi1[g] = __shfl(i1, g * 8, 64);
            gi2[g] = __shfl(i2, g * 8, 64);
            gsc[g] = gv1[g] + gv2[g];
        }

        // top-4 groups by score (ties -> lowest group index)
        float cp[8]; int cid[8];
        int usedmask = 0;
        #pragma unroll
        for (int r = 0; r < 4; ++r) {
            float best = -1.0f; int bg = 0;
            float b1 = 0.f, b2 = 0.f; int bi1 = 0, bi2 = 0;
            #pragma unroll
            for (int g = 0; g < 8; ++g) {
                const bool ok = (((usedmask >> g) & 1) == 0) && (gsc[g] > best);
                if (ok) { best = gsc[g]; bg = g;
                          b1 = gv1[g]; b2 = gv2[g]; bi1 = gi1[g]; bi2 = gi2[g]; }
            }
            usedmask |= (1 << bg);
            cp[2 * r] = b1; cp[2 * r + 1] = b2;
            cid[2 * r] = bi1; cid[2 * r + 1] = bi2;
        }

        float wsum = 1e-9f;
        #pragma unroll
        for (int j = 0; j < 8; ++j) wsum += cp[j];
        const float winv = 1.0f / wsum;

        if (lane == 0) {
            #pragma unroll
            for (int j = 0; j < 8; ++j) {
                out_w[(size_t)tok * 8 + j] = cp[j] * winv;
                out_id[(size_t)tok * 8 + j] = (float)cid[j];
            }
            atomicAdd(&lds_cnt[cid[0]], 1.0f);
        }
    }

    // block-level psum reduction, then one global atomic per expert
    atomicAdd(&lds_psum[lane * 4 + 0], r0);
    atomicAdd(&lds_psum[lane * 4 + 1], r1);
    atomicAdd(&lds_psum[lane * 4 + 2], r2);
    atomicAdd(&lds_psum[lane * 4 + 3], r3);
    __syncthreads();
    if (t < 256) {
        atomicAdd(&g_psum[t], lds_psum[t]);
        const float c = lds_cnt[t];
        if (c != 0.0f) atomicAdd(&g_cnt[t], c);
    }
}

// ---------------------------------------------------------------------------
// Kernel 2: aux_loss = E * sum_e (cnt_e/T) * (psum_e/T)
// ---------------------------------------------------------------------------
__global__ __launch_bounds__(256)
void aux_kernel(const float* __restrict__ g_psum, const float* __restrict__ g_cnt,
                float* __restrict__ out_aux) {
    __shared__ float red[E_EXP];
    const int t = threadIdx.x;
    const float invT = 1.0f / (float)T_TOK;
    red[t] = (g_cnt[t] * invT) * (g_psum[t] * invT);
    __syncthreads();
    #pragma unroll
    for (int s = 128; s > 0; s >>= 1) {
        if (t < s) red[t] += red[t + s];
        __syncthreads();
    }
    if (t == 0) out_aux[0] = (float)E_EXP * red[0];
}

// ---------------------------------------------------------------------------
extern "C" void kernel_launch(void* const* d_in, const int* in_sizes, int n_in,
                              void* d_out, int out_size, void* d_ws, size_t ws_size,
                              hipStream_t stream) {
    const float* x = (const float*)d_in[0];
    const float* W = (const float*)d_in[1];

    float* out = (float*)d_out;
    float* out_w = out;                       // 16384*8
    float* out_id = out + T_TOK * 8;          // 16384*8 (ids stored as floats)
    float* out_aux = out + 2 * T_TOK * 8;     // 1

    float* g_psum = (float*)d_ws;                       // 256
    float* g_cnt = g_psum + E_EXP;                      // 256
    uint16_t* Wh = (uint16_t*)(g_psum + 512);           // 2 MB
    uint16_t* Wm = Wh + (size_t)E_EXP * D_DIM;          // 2 MB
    uint16_t* Wl = Wm + (size_t)E_EXP * D_DIM;          // 2 MB

    wsplit_kernel<<<1024, 256, 0, stream>>>(W, Wh, Wm, Wl, g_psum);
    gemm_router_kernel<<<T_TOK / 32, 512, 0, stream>>>(
        x, Wh, Wm, Wl, out_w, out_id, g_psum, g_cnt);
    aux_kernel<<<1, 256, 0, stream>>>(g_psum, g_cnt, out_aux);
}

// Round 8
// 477.831 us; speedup vs baseline: 1.4616x; 1.4616x over previous
//
#include <hip/hip_runtime.h>
#include <hip/hip_bf16.h>
#include <stdint.h>

#define T_TOK 16384
#define D_DIM 4096
#define E_EXP 256

typedef __attribute__((ext_vector_type(8))) short bf16x8;
typedef __attribute__((ext_vector_type(4))) float f32x4;

__device__ __forceinline__ uint32_t bf16_rne(float f) {
    uint32_t u = __float_as_uint(f);
    return (u + 0x7FFFu + ((u >> 16) & 1u)) >> 16;
}

// ---------------------------------------------------------------------------
// Kernel 0: split W into 3 bf16 terms (h+m+l, RNE at each level), stored in
// PACKED MFMA-FRAGMENT ORDER, + zero accs.
// Packed layout (uint16 units): tile = 16 experts x 32 k = 512 elems (1 KB).
//   addr(e,k) = (tile_e*128 + tile_k)*512 + quad*128 + l16*8 + (k&7)
//   where tile_e=e>>4, l16=e&15, tile_k=k>>5, quad=(k>>3)&3.
// A wave's B-fragment load becomes base + lane*16B: one contiguous 1 KB read.
// ---------------------------------------------------------------------------
__global__ __launch_bounds__(256)
void wsplit_kernel(const float* __restrict__ W, uint16_t* __restrict__ Wh,
                   uint16_t* __restrict__ Wm, uint16_t* __restrict__ Wl,
                   float* __restrict__ acc512) {
    const int idx = blockIdx.x * 256 + threadIdx.x;  // 0..262143 float4s
    const int e = idx >> 10;              // expert row
    const int k0 = (idx & 1023) * 4;      // k offset (multiple of 4)
    const float4 v = ((const float4*)W)[idx];
    const float f[4] = {v.x, v.y, v.z, v.w};
    uint32_t h[4], m[4], l[4];
    #pragma unroll
    for (int j = 0; j < 4; ++j) {
        h[j] = bf16_rne(f[j]);
        const float r1 = f[j] - __uint_as_float(h[j] << 16);  // exact
        m[j] = bf16_rne(r1);
        const float r2 = r1 - __uint_as_float(m[j] << 16);    // exact
        l[j] = bf16_rne(r2);
    }
    // packed destination (4 consecutive uint16 inside one 8-elem group)
    const uint32_t addr_u16 = (uint32_t)((e >> 4) * 128 + (k0 >> 5)) * 512
                            + ((k0 >> 3) & 3) * 128 + (e & 15) * 8 + (k0 & 7);
    const uint32_t du2 = addr_u16 >> 2;   // uint2 index (8-byte aligned)
    ((uint2*)Wh)[du2] = make_uint2(h[0] | (h[1] << 16), h[2] | (h[3] << 16));
    ((uint2*)Wm)[du2] = make_uint2(m[0] | (m[1] << 16), m[2] | (m[3] << 16));
    ((uint2*)Wl)[du2] = make_uint2(l[0] | (l[1] << 16), l[2] | (l[3] << 16));
    if (blockIdx.x == 0) {
        acc512[threadIdx.x] = 0.0f;
        acc512[threadIdx.x + 256] = 0.0f;
    }
}

// ---------------------------------------------------------------------------
// Kernel 1 (FUSED): logits tile = x @ W^T (split-3 bf16, 6 MFMA products)
// + in-block softmax / grouped top-k router. R7/R8: R5 geometry
// (64 tok x 256 exp per block, 8 waves, grid 256) -- R6's 32-tok split
// doubled W traffic and halved MFMA:B ratio, regressing 322->455 us.
// ONLY change vs R5: B is read from the packed fragment-order buffers
// (coalesced 1 KB wave-reads instead of 16-way scattered row reads).
// Same values, same MFMA order -> logits bit-identical.
// ---------------------------------------------------------------------------
#define LDK 72
#define SROW 272  // f32 row stride of the LDS logits half-tile (bank-spread)

#define LOADB(bh, bm, bl, ko) do { \
    _Pragma("unroll") \
    for (int nt = 0; nt < 2; ++nt) { \
        const uint32_t o = wbase[nt] + (uint32_t)((ko) >> 5) * 512; \
        bh[nt] = *(const bf16x8*)(Wh + o); \
        bm[nt] = *(const bf16x8*)(Wm + o); \
        bl[nt] = *(const bf16x8*)(Wl + o); \
    } } while (0)

#define SPLIT_STORE(buf) do { \
    const float f[8] = {p0.x, p0.y, p0.z, p0.w, p1.x, p1.y, p1.z, p1.w}; \
    uint32_t h[8], m[8], l[8]; \
    _Pragma("unroll") \
    for (int j = 0; j < 8; ++j) { \
        h[j] = bf16_rne(f[j]); \
        const float r1 = f[j] - __uint_as_float(h[j] << 16); \
        m[j] = bf16_rne(r1); \
        const float r2 = r1 - __uint_as_float(m[j] << 16); \
        l[j] = bf16_rne(r2); \
    } \
    uint4 hv, mv, lv; \
    hv.x = h[0] | (h[1] << 16); hv.y = h[2] | (h[3] << 16); \
    hv.z = h[4] | (h[5] << 16); hv.w = h[6] | (h[7] << 16); \
    mv.x = m[0] | (m[1] << 16); mv.y = m[2] | (m[3] << 16); \
    mv.z = m[4] | (m[5] << 16); mv.w = m[6] | (m[7] << 16); \
    lv.x = l[0] | (l[1] << 16); lv.y = l[2] | (l[3] << 16); \
    lv.z = l[4] | (l[5] << 16); lv.w = l[6] | (l[7] << 16); \
    *(uint4*)&sXh[(buf) * 4608 + swoff] = hv; \
    *(uint4*)&sXm[(buf) * 4608 + swoff] = mv; \
    *(uint4*)&sXl[(buf) * 4608 + swoff] = lv; \
} while (0)

#define COMPUTE(buf, s, bh, bm, bl) do { \
    bf16x8 ah[4], am[4], al[4]; \
    _Pragma("unroll") \
    for (int mt = 0; mt < 4; ++mt) { \
        const int ro = (buf) * 4608 + (mt * 16 + l16) * LDK + (s) * 32 + quad * 8; \
        ah[mt] = *(const bf16x8*)&sXh[ro]; \
        am[mt] = *(const bf16x8*)&sXm[ro]; \
        al[mt] = *(const bf16x8*)&sXl[ro]; \
    } \
    _Pragma("unroll") \
    for (int mt = 0; mt < 4; ++mt) \
        _Pragma("unroll") \
        for (int nt = 0; nt < 2; ++nt) \
            acc[mt][nt] = __builtin_amdgcn_mfma_f32_16x16x32_bf16(ah[mt], bh[nt], acc[mt][nt], 0, 0, 0); \
    _Pragma("unroll") \
    for (int mt = 0; mt < 4; ++mt) \
        _Pragma("unroll") \
        for (int nt = 0; nt < 2; ++nt) \
            acc[mt][nt] = __builtin_amdgcn_mfma_f32_16x16x32_bf16(ah[mt], bm[nt], acc[mt][nt], 0, 0, 0); \
    _Pragma("unroll") \
    for (int mt = 0; mt < 4; ++mt) \
        _Pragma("unroll") \
        for (int nt = 0; nt < 2; ++nt) \
            acc[mt][nt] = __builtin_amdgcn_mfma_f32_16x16x32_bf16(am[mt], bh[nt], acc[mt][nt], 0, 0, 0); \
    _Pragma("unroll") \
    for (int mt = 0; mt < 4; ++mt) \
        _Pragma("unroll") \
        for (int nt = 0; nt < 2; ++nt) \
            acc[mt][nt] = __builtin_amdgcn_mfma_f32_16x16x32_bf16(am[mt], bm[nt], acc[mt][nt], 0, 0, 0); \
    _Pragma("unroll") \
    for (int mt = 0; mt < 4; ++mt) \
        _Pragma("unroll") \
        for (int nt = 0; nt < 2; ++nt) \
            acc[mt][nt] = __builtin_amdgcn_mfma_f32_16x16x32_bf16(ah[mt], bl[nt], acc[mt][nt], 0, 0, 0); \
    _Pragma("unroll") \
    for (int mt = 0; mt < 4; ++mt) \
        _Pragma("unroll") \
        for (int nt = 0; nt < 2; ++nt) \
            acc[mt][nt] = __builtin_amdgcn_mfma_f32_16x16x32_bf16(al[mt], bh[nt], acc[mt][nt], 0, 0, 0); \
} while (0)

__global__ __launch_bounds__(512, 2)
void gemm_router_kernel(const float* __restrict__ x,
                        const uint16_t* __restrict__ Wh,
                        const uint16_t* __restrict__ Wm,
                        const uint16_t* __restrict__ Wl,
                        float* __restrict__ out_w,
                        float* __restrict__ out_id,
                        float* __restrict__ g_psum,
                        float* __restrict__ g_cnt) {
    // One 55296-byte pool, time-shared:
    //  gemm phase : sXh[2][4608] | sXm[2][4608] | sXl[2][4608]  (uint16)
    //  route phase: sLog f32[32][SROW] (34816 B) | lds_psum[256] | lds_cnt[256]
    __shared__ __align__(16) char pool[55296];
    uint16_t* sXh = (uint16_t*)pool;
    uint16_t* sXm = (uint16_t*)(pool + 18432);
    uint16_t* sXl = (uint16_t*)(pool + 36864);
    float* sLog = (float*)pool;
    float* lds_psum = (float*)(pool + 34816);
    float* lds_cnt = (float*)(pool + 35840);

    const int t = threadIdx.x;
    const int tok0 = blockIdx.x * 64;
    const int wave = t >> 6, lane = t & 63;
    const int quad = lane >> 4, l16 = lane & 15;

    // staging: 512 threads, each handles 8 consecutive k of one token
    const int stok = t >> 3;        // 0..63
    const int skoff = (t & 7) * 8;  // 0,8,..,56
    const float* xp = x + (size_t)(tok0 + stok) * D_DIM + skoff;
    const int swoff = stok * LDK + skoff;

    // B bases in packed layout: wave covers experts [wave*32, wave*32+32)
    // tile_e = wave*2 + nt; base = tile_e*128*512 + lane*8 (uint16 units)
    uint32_t wbase[2];
    #pragma unroll
    for (int nt = 0; nt < 2; ++nt)
        wbase[nt] = (uint32_t)(wave * 2 + nt) * 65536 + (uint32_t)lane * 8;

    const f32x4 zf = {0.f, 0.f, 0.f, 0.f};
    f32x4 acc[4][2];
    #pragma unroll
    for (int mt = 0; mt < 4; ++mt)
        #pragma unroll
        for (int nt = 0; nt < 2; ++nt) acc[mt][nt] = zf;

    // ---- prologue ----
    float4 p0 = ((const float4*)xp)[0];
    float4 p1 = ((const float4*)xp)[1];
    bf16x8 cbh[2], cbm[2], cbl[2], nbh[2], nbm[2], nbl[2];

    SPLIT_STORE(0);                       // x tile kb=0 -> buf 0
    LOADB(cbh, cbm, cbl, 0);              // B frags (kb=0, s=0)
    {   // prefetch x tile kb=64
        const float* xn = xp + 64;
        p0 = ((const float4*)xn)[0];
        p1 = ((const float4*)xn)[1];
    }
    __syncthreads();

    for (int kb = 0; kb < D_DIM; kb += 64) {
        const int cur = (kb >> 6) & 1;
        // ---- phase s=0 ----
        LOADB(nbh, nbm, nbl, kb + 32);            // this k-step, s=1
        COMPUTE(cur, 0, cbh, cbm, cbl);
        // ---- phase s=1 ----
        if (kb + 64 < D_DIM) {
            LOADB(cbh, cbm, cbl, kb + 64);        // next k-step, s=0
            SPLIT_STORE(cur ^ 1);                 // stage next x tile
        }
        if (kb + 128 < D_DIM) {                   // prefetch x tile t+2
            const float* xn = xp + kb + 128;
            p0 = ((const float4*)xn)[0];
            p1 = ((const float4*)xn)[1];
        }
        COMPUTE(cur, 1, nbh, nbm, nbl);
        __syncthreads();
    }

    // ================= fused router epilogue =================
    if (t < 256) { lds_psum[t] = 0.0f; lds_cnt[t] = 0.0f; }

    float r0 = 0.f, r1 = 0.f, r2 = 0.f, r3 = 0.f;

    #pragma unroll
    for (int hh = 0; hh < 2; ++hh) {
        // write this half's logits (tokens hh*32 .. hh*32+31) to LDS.
        // C/D layout: token = mt*16 + quad*4 + r, expert = wave*32 + nt*16 + l16
        #pragma unroll
        for (int u = 0; u < 2; ++u)
            #pragma unroll
            for (int nt = 0; nt < 2; ++nt)
                #pragma unroll
                for (int r = 0; r < 4; ++r)
                    sLog[(u * 16 + quad * 4 + r) * SROW + wave * 32 + nt * 16 + l16] =
                        acc[hh * 2 + u][nt][r];
        __syncthreads();

        // route 4 tokens per wave (identical math to the standalone router)
        #pragma unroll
        for (int it = 0; it < 4; ++it) {
            const int lrow = wave * 4 + it;              // 0..31 within half
            const int tok = tok0 + hh * 32 + lrow;       // global token
            const float4 lg = *(const float4*)&sLog[lrow * SROW + lane * 4];

            float mx = fmaxf(fmaxf(lg.x, lg.y), fmaxf(lg.z, lg.w));
            #pragma unroll
            for (int off = 32; off >= 1; off >>= 1)
                mx = fmaxf(mx, __shfl_xor(mx, off, 64));
            float p0_ = __expf(lg.x - mx);
            float p1_ = __expf(lg.y - mx);
            float p2_ = __expf(lg.z - mx);
            float p3_ = __expf(lg.w - mx);
            float sm = p0_ + p1_ + p2_ + p3_;
            #pragma unroll
            for (int off = 32; off >= 1; off >>= 1)
                sm += __shfl_xor(sm, off, 64);
            const float inv = 1.0f / sm;
            p0_ *= inv; p1_ *= inv; p2_ *= inv; p3_ *= inv;
            r0 += p0_; r1 += p1_; r2 += p2_; r3 += p3_;

            // per-lane top-2 of 4 (ties -> lowest index, matching lax.top_k)
            const int e0 = lane * 4;
            float v1 = p0_, v2 = p1_; int i1 = e0, i2 = e0 + 1;
            if (p1_ > p0_) { v1 = p1_; i1 = e0 + 1; v2 = p0_; i2 = e0; }
            if (p2_ > v1)      { v2 = v1; i2 = i1; v1 = p2_; i1 = e0 + 2; }
            else if (p2_ > v2) { v2 = p2_; i2 = e0 + 2; }
            if (p3_ > v1)      { v2 = v1; i2 = i1; v1 = p3_; i1 = e0 + 3; }
            else if (p3_ > v2) { v2 = p3_; i2 = e0 + 3; }

            // merge top-2 across the 8 lanes of each group
            #pragma unroll
            for (int off = 1; off <= 4; off <<= 1) {
                const float ov1 = __shfl_xor(v1, off, 64);
                const int   oi1 = __shfl_xor(i1, off, 64);
                const float ov2 = __shfl_xor(v2, off, 64);
                const int   oi2 = __shfl_xor(i2, off, 64);
                float n1, n2; int ni1, ni2;
                const bool o_first = (ov1 > v1) || (ov1 == v1 && oi1 < i1);
                if (o_first) {
                    n1 = ov1; ni1 = oi1;
                    const bool s = (ov2 > v1) || (ov2 == v1 && oi2 < i1);
                    n2 = s ? ov2 : v1; ni2 = s ? oi2 : i1;
                } else {
                    n1 = v1; ni1 = i1;
                    const bool s = (ov1 > v2) || (ov1 == v2 && oi1 < i2);
                    n2 = s ? ov1 : v2; ni2 = s ? oi1 : i2;
                }
                v1 = n1; i1 = ni1; v2 = n2; i2 = ni2;
            }

            // gather all 8 groups' results to every lane
            float gv1[8], gv2[8], gsc[8]; int gi1[8], gi2[8];
            #pragma unroll
            for (int g = 0; g < 8; ++g) {
                gv1[g] = __shfl(v1, g * 8, 64);
                gv2[g] = __shfl(v2, g * 8, 64);
                gi1[g] = __shfl(i1, g * 8, 64);
                gi2[g] = __shfl(i2, g * 8, 64);
                gsc[g] = gv1[g] + gv2[g];
            }

            // top-4 groups by score (ties -> lowest group index)
            float cp[8]; int cid[8];
            int usedmask = 0;
            #pragma unroll
            for (int r = 0; r < 4; ++r) {
                float best = -1.0f; int bg = 0;
                float b1 = 0.f, b2 = 0.f; int bi1 = 0, bi2 = 0;
                #pragma unroll
                for (int g = 0; g < 8; ++g) {
                    const bool ok = (((usedmask >> g) & 1) == 0) && (gsc[g] > best);
                    if (ok) { best = gsc[g]; bg = g;
                              b1 = gv1[g]; b2 = gv2[g]; bi1 = gi1[g]; bi2 = gi2[g]; }
                }
                usedmask |= (1 << bg);
                cp[2 * r] = b1; cp[2 * r + 1] = b2;
                cid[2 * r] = bi1; cid[2 * r + 1] = bi2;
            }

            float wsum = 1e-9f;
            #pragma unroll
            for (int j = 0; j < 8; ++j) wsum += cp[j];
            const float winv = 1.0f / wsum;

            if (lane == 0) {
                #pragma unroll
                for (int j = 0; j < 8; ++j) {
                    out_w[(size_t)tok * 8 + j] = cp[j] * winv;
                    out_id[(size_t)tok * 8 + j] = (float)cid[j];
                }
                atomicAdd(&lds_cnt[cid[0]], 1.0f);
            }
        }
        __syncthreads();   // half done: safe to overwrite sLog / read lds_cnt
    }

    // block-level psum reduction, then one global atomic per expert
    atomicAdd(&lds_psum[lane * 4 + 0], r0);
    atomicAdd(&lds_psum[lane * 4 + 1], r1);
    atomicAdd(&lds_psum[lane * 4 + 2], r2);
    atomicAdd(&lds_psum[lane * 4 + 3], r3);
    __syncthreads();
    if (t < 256) {
        atomicAdd(&g_psum[t], lds_psum[t]);
        const float c = lds_cnt[t];
        if (c != 0.0f) atomicAdd(&g_cnt[t], c);
    }
}

// ---------------------------------------------------------------------------
// Kernel 2: aux_loss = E * sum_e (cnt_e/T) * (psum_e/T)
// ---------------------------------------------------------------------------
__global__ __launch_bounds__(256)
void aux_kernel(const float* __restrict__ g_psum, const float* __restrict__ g_cnt,
                float* __restrict__ out_aux) {
    __shared__ float red[E_EXP];
    const int t = threadIdx.x;
    const float invT = 1.0f / (float)T_TOK;
    red[t] = (g_cnt[t] * invT) * (g_psum[t] * invT);
    __syncthreads();
    #pragma unroll
    for (int s = 128; s > 0; s >>= 1) {
        if (t < s) red[t] += red[t + s];
        __syncthreads();
    }
    if (t == 0) out_aux[0] = (float)E_EXP * red[0];
}

// ---------------------------------------------------------------------------
extern "C" void kernel_launch(void* const* d_in, const int* in_sizes, int n_in,
                              void* d_out, int out_size, void* d_ws, size_t ws_size,
                              hipStream_t stream) {
    const float* x = (const float*)d_in[0];
    const float* W = (const float*)d_in[1];

    float* out = (float*)d_out;
    float* out_w = out;                       // 16384*8
    float* out_id = out + T_TOK * 8;          // 16384*8 (ids stored as floats)
    float* out_aux = out + 2 * T_TOK * 8;     // 1

    float* g_psum = (float*)d_ws;                       // 256
    float* g_cnt = g_psum + E_EXP;                      // 256
    uint16_t* Wh = (uint16_t*)(g_psum + 512);           // 2 MB (packed)
    uint16_t* Wm = Wh + (size_t)E_EXP * D_DIM;          // 2 MB (packed)
    uint16_t* Wl = Wm + (size_t)E_EXP * D_DIM;          // 2 MB (packed)

    wsplit_kernel<<<1024, 256, 0, stream>>>(W, Wh, Wm, Wl, g_psum);
    gemm_router_kernel<<<T_TOK / 64, 512, 0, stream>>>(
        x, Wh, Wm, Wl, out_w, out_id, g_psum, g_cnt);
    aux_kernel<<<1, 256, 0, stream>>>(g_psum, g_cnt, out_aux);
}